// Round 4
// baseline (261.942 us; speedup 1.0000x reference)
//
#include <hip/hip_runtime.h>
#include <stdint.h>

typedef __attribute__((ext_vector_type(8))) _Float16 f16x8;
typedef __attribute__((ext_vector_type(8))) short bf16x8;
typedef __attribute__((ext_vector_type(16))) float f32x16;

#define BH_ 64
#define S_ 2048
#define D_ 64
#define KT_ 64
#define NT_ (S_ / KT_)
#define LOG2E 1.44269504088896340736f
#define DEFER_THR 8.0f

#define WS_ARR ((size_t)BH_ * S_ * D_ * 2)   // 16 MB per 16-bit array
#define WS_NEED (2 * WS_ARR)                 // Kf Vt

__device__ __forceinline__ uint16_t f32_to_bf16_rn(float f) {
    uint32_t u = __float_as_uint(f);
    u += 0x7fffu + ((u >> 16) & 1u);
    return (uint16_t)(u >> 16);
}
__device__ __forceinline__ float bfbits_to_f32(uint16_t h) {
    return __uint_as_float(((uint32_t)h) << 16);
}
__device__ __forceinline__ float phi(float x) { return x > 0.0f ? x + 1.0f : __expf(x); }

#if __has_builtin(__builtin_amdgcn_exp2f)
#define EXP2F(x) __builtin_amdgcn_exp2f(x)
#else
#define EXP2F(x) exp2f(x)
#endif

__device__ __forceinline__ float fmax3(float a, float b, float c) {
    float d;
    asm("v_max3_f32 %0, %1, %2, %3" : "=v"(d) : "v"(a), "v"(b), "v"(c));
    return d;
}

__device__ __forceinline__ uint32_t pkrtz(float lo, float hi2) {
    union {
        decltype(__builtin_amdgcn_cvt_pkrtz(0.0f, 0.0f)) v;
        uint32_t u;
    } c;
    c.v = __builtin_amdgcn_cvt_pkrtz(lo, hi2);
    return c.u;
}

// ---------------- pre-pass kernels (LINEAR layouts — no LDS swizzle needed) --

// Kf[bh][t][d] = f16(phi(K[bh][t][d])) — identity layout, pure map.
__global__ void prep_k(const float* __restrict__ K, uint16_t* __restrict__ Kf) {
    const size_t e = ((size_t)blockIdx.x * 256 + threadIdx.x) * 8;
    const float4 a = *(const float4*)(K + e);
    const float4 b = *(const float4*)(K + e + 4);
    const float xs[8] = {a.x, a.y, a.z, a.w, b.x, b.y, b.z, b.w};
    _Float16 h8[8];
#pragma unroll
    for (int j = 0; j < 8; ++j) h8[j] = (_Float16)phi(xs[j]);
    *(f16x8*)(Kf + e) = *(const f16x8*)h8;
}

// V^T per (bh,kt) tile: Vt[tile][d][tperm] with t-rows tau-permuted (swap
// t-blocks [4..7] <-> [8..11] per 16) so P fragments feed PV's B-operand
// with NO cross-lane exchange. Linear in d (row) and chunk (col).
__global__ void prep_v(const float* __restrict__ V, uint16_t* __restrict__ Vt) {
    const int bh = blockIdx.x >> 5, kt = blockIdx.x & 31;
    const int d = threadIdx.x >> 2;
    const size_t tile = (size_t)(bh * 32 + kt) * 4096;
    const float* vb = V + ((size_t)bh * S_ + (size_t)kt * KT_) * D_ + d;
#pragma unroll
    for (int cc = 0; cc < 2; ++cc) {
        const int ct = (threadIdx.x & 3) * 2 + cc;
        _Float16 v8[8];
#pragma unroll
        for (int i = 0; i < 8; ++i) {
            const int pos = 8 * ct + i;
            const int src = (pos & 48) | (4 * ((pos >> 3) & 1) + (pos & 3) + 8 * ((pos >> 2) & 1));
            v8[i] = (_Float16)vb[(size_t)src * D_];
        }
        *(f16x8*)(Vt + tile + (size_t)d * 64 + (size_t)ct * 8) = *(const f16x8*)v8;
    }
}

// ---------------- main kernel: 8 waves / 512 threads, 256 q-rows per block ----
// NO LDS, NO barriers: per-tile K/V working set (16 KB) is L1-resident and
// per-XCD working set (8 bh x 512 KB = 4 MB) is L2-resident under the XCD
// swizzle, so fragments are read straight from cache. Waves are fully
// independent. Pipelining at zero net register cost:
//   - K chunk-0 of tile t+1 prefetched during PV(t)      (+8 regs persistent)
//   - V chunks 0,1 loaded before softmax (hidden under ~600cy VALU)
//   - V chunks 2,3 issued after pkrtz (s dead), consumed after 4 MFMAs

__global__ __launch_bounds__(512, 4)
void la_attn8(const float* __restrict__ Q, const uint16_t* __restrict__ Kf,
              const uint16_t* __restrict__ Vt, float* __restrict__ O)
{
    const int id = blockIdx.x;                 // 0..511
    const int wg = (id & 7) * 64 + (id >> 3);  // bijective XCD-chunked swizzle
    const int bh = wg >> 3;                    // 8 consecutive wg share one bh
    const int qt = wg & 7;
    const int tid = threadIdx.x;
    const int lane = tid & 63;
    const int wid = tid >> 6;                  // 0..7
    const int ln31 = lane & 31;
    const int hi = lane >> 5;

    const int q0 = qt * 256 + wid * 32;

    // ---- Q: phi-map from raw fp32 in-kernel (once per block lifetime)
    f16x8 qf[4];
    {
        const float* qp = Q + ((size_t)bh * S_ + q0 + ln31) * 64;
#pragma unroll
        for (int m = 0; m < 4; ++m) {
            const float4 a = *(const float4*)(qp + m * 16 + hi * 8);
            const float4 b = *(const float4*)(qp + m * 16 + hi * 8 + 4);
            const float xs[8] = {a.x, a.y, a.z, a.w, b.x, b.y, b.z, b.w};
            _Float16 h8[8];
#pragma unroll
            for (int j = 0; j < 8; ++j) h8[j] = (_Float16)(phi(xs[j]) * LOG2E);
            qf[m] = *(const f16x8*)h8;
        }
    }

    f32x16 accO0 = (f32x16)0.0f, accO1 = (f32x16)0.0f;
    float m_run = 0.0f, l_run = 0.0f;   // m_run=0: first tile takes rescale branch

    // per-lane fragment base pointers (chunk m at +m*16, +32 k/d-rows at +2048)
    const size_t tb0 = (size_t)bh * 32 * 4096;
    const uint16_t* kptr = Kf + tb0 + (size_t)ln31 * 64 + hi * 8;
    const uint16_t* vptr = Vt + tb0 + (size_t)ln31 * 64 + hi * 8;

    // preload K chunk 0 of tile 0 (L2-resident from prep_k writeback)
    f16x8 kA = *(const f16x8*)(kptr);
    f16x8 kB = *(const f16x8*)(kptr + 2048);

    for (int kt = 0; kt < NT_; ++kt) {
        // ---- QK^T, swapped operands; chunk m+1 loads pipelined 1 ahead
        f32x16 s0, s1;
#pragma unroll
        for (int r = 0; r < 16; ++r) { s0[r] = -m_run; s1[r] = -m_run; }
        __builtin_amdgcn_s_setprio(1);
#pragma unroll
        for (int m = 0; m < 4; ++m) {
            f16x8 kn0, kn1;
            if (m < 3) {
                kn0 = *(const f16x8*)(kptr + (m + 1) * 16);
                kn1 = *(const f16x8*)(kptr + (m + 1) * 16 + 2048);
            }
            s0 = __builtin_amdgcn_mfma_f32_32x32x16_f16(kA, qf[m], s0, 0, 0, 0);
            s1 = __builtin_amdgcn_mfma_f32_32x32x16_f16(kB, qf[m], s1, 0, 0, 0);
            if (m < 3) { kA = kn0; kB = kn1; }
        }
        __builtin_amdgcn_s_setprio(0);
        kptr += 4096;

        // ---- V chunks 0,1 issued now; latency hides under softmax VALU
        f16x8 v0 = *(const f16x8*)(vptr);
        f16x8 v1 = *(const f16x8*)(vptr + 2048);
        f16x8 v2 = *(const f16x8*)(vptr + 16);
        f16x8 v3 = *(const f16x8*)(vptr + 16 + 2048);

        // ---- merged online softmax over all 64 k-rows (scores pre-shifted)
        float t8[8];
#pragma unroll
        for (int r = 0; r < 8; ++r)
            t8[r] = fmax3(fmaxf(s0[r], s0[r + 8]), s1[r], s1[r + 8]);
        const float ta = fmax3(t8[0], t8[1], t8[2]);
        const float tb = fmax3(t8[3], t8[4], t8[5]);
        const float tc = fmaxf(t8[6], t8[7]);
        float tmax = fmax3(ta, tb, tc);
        tmax = fmaxf(tmax, __shfl_xor(tmax, 32));   // = max(s) - m_run

        if (!__all(tmax <= DEFER_THR)) {     // T13 defer-max (rare)
            const float dlt = fmaxf(tmax, 0.0f);
            const float corr = EXP2F(-dlt);
            m_run += dlt;
            l_run *= corr;
#pragma unroll
            for (int r = 0; r < 16; ++r) {
                accO0[r] *= corr; accO1[r] *= corr;
                s0[r] -= dlt; s1[r] -= dlt;
            }
        }
        float ps0 = 0.0f, ps1 = 0.0f;
#pragma unroll
        for (int r = 0; r < 16; ++r) {
            const float p0 = EXP2F(s0[r]);
            const float p1 = EXP2F(s1[r]);
            s0[r] = p0; s1[r] = p1;
            ps0 += p0; ps1 += p1;
        }
        l_run += ps0 + ps1;

        // ---- P -> f16 fragments (no exchange: V is tau-permuted); s dies here
        union PF { uint32_t u[4]; f16x8 v; };
        PF pf0, pf1, pf2, pf3;
#pragma unroll
        for (int i = 0; i < 4; ++i) {
            pf0.u[i] = pkrtz(s0[2 * i], s0[2 * i + 1]);
            pf1.u[i] = pkrtz(s0[8 + 2 * i], s0[9 + 2 * i]);
            pf2.u[i] = pkrtz(s1[2 * i], s1[2 * i + 1]);
            pf3.u[i] = pkrtz(s1[8 + 2 * i], s1[9 + 2 * i]);
        }

        // ---- V chunks 2,3 + next-tile K chunk-0 prefetch (hide under PV)
        f16x8 v4 = *(const f16x8*)(vptr + 32);
        f16x8 v5 = *(const f16x8*)(vptr + 32 + 2048);
        f16x8 v6 = *(const f16x8*)(vptr + 48);
        f16x8 v7 = *(const f16x8*)(vptr + 48 + 2048);
        vptr += 4096;
        if (kt + 1 < NT_) {
            kA = *(const f16x8*)(kptr);
            kB = *(const f16x8*)(kptr + 2048);
        }

        // ---- PV: O^T += V'^T . P  (chunk c = sub*2 + ts)
        __builtin_amdgcn_s_setprio(1);
        accO0 = __builtin_amdgcn_mfma_f32_32x32x16_f16(v0, pf0.v, accO0, 0, 0, 0);
        accO1 = __builtin_amdgcn_mfma_f32_32x32x16_f16(v1, pf0.v, accO1, 0, 0, 0);
        accO0 = __builtin_amdgcn_mfma_f32_32x32x16_f16(v2, pf1.v, accO0, 0, 0, 0);
        accO1 = __builtin_amdgcn_mfma_f32_32x32x16_f16(v3, pf1.v, accO1, 0, 0, 0);
        accO0 = __builtin_amdgcn_mfma_f32_32x32x16_f16(v4, pf2.v, accO0, 0, 0, 0);
        accO1 = __builtin_amdgcn_mfma_f32_32x32x16_f16(v5, pf2.v, accO1, 0, 0, 0);
        accO0 = __builtin_amdgcn_mfma_f32_32x32x16_f16(v6, pf3.v, accO0, 0, 0, 0);
        accO1 = __builtin_amdgcn_mfma_f32_32x32x16_f16(v7, pf3.v, accO1, 0, 0, 0);
        __builtin_amdgcn_s_setprio(0);
    }

    // ---- epilogue: combine partner l, normalize, write O[q][d]
    const float l_tot = l_run + __shfl_xor(l_run, 32);
    const float inv = 1.0f / l_tot;
    float* op = O + ((size_t)bh * S_ + q0 + ln31) * D_;
#pragma unroll
    for (int g = 0; g < 4; ++g) {
        float4 o0, o1;
        o0.x = accO0[4 * g + 0] * inv; o0.y = accO0[4 * g + 1] * inv;
        o0.z = accO0[4 * g + 2] * inv; o0.w = accO0[4 * g + 3] * inv;
        o1.x = accO1[4 * g + 0] * inv; o1.y = accO1[4 * g + 1] * inv;
        o1.z = accO1[4 * g + 2] * inv; o1.w = accO1[4 * g + 3] * inv;
        *(float4*)(op + 8 * g + 4 * hi) = o0;
        *(float4*)(op + 32 + 8 * g + 4 * hi) = o1;
    }
}

// ---------------- fallback (round-1, self-contained) ----------------

__global__ __launch_bounds__(256, 2)
void la_attn_fwd(const float* __restrict__ Q, const float* __restrict__ K,
                 const float* __restrict__ V, float* __restrict__ O)
{
    const int bh = blockIdx.x;
    const int qt = blockIdx.y;
    const int tid = threadIdx.x;
    const int lane = tid & 63;
    const int wid = tid >> 6;
    const int ln31 = lane & 31;
    const int hi = lane >> 5;

    const size_t base = (size_t)bh * (S_ * D_);
    const float* __restrict__ Qb = Q + base;
    const float* __restrict__ Kb = K + base;
    const float* __restrict__ Vb = V + base;
    float* __restrict__ Ob = O + base;

    __shared__ __align__(16) uint16_t kh[32][D_];
    __shared__ __align__(16) uint16_t kl[32][D_];

    const int q0 = qt * 128 + wid * 32;

    bf16x8 qfh[4], qfl[4];
    {
        const float* qp = Qb + (size_t)(q0 + ln31) * D_;
#pragma unroll
        for (int m = 0; m < 4; ++m) {
            const float4 a = *(const float4*)(qp + m * 16 + hi * 8);
            const float4 b = *(const float4*)(qp + m * 16 + hi * 8 + 4);
            float xs[8] = {a.x, a.y, a.z, a.w, b.x, b.y, b.z, b.w};
#pragma unroll
            for (int j = 0; j < 8; ++j) {
                float x = phi(xs[j]);
                uint16_t h = f32_to_bf16_rn(x);
                qfh[m][j] = (short)h;
                qfl[m][j] = (short)f32_to_bf16_rn(x - bfbits_to_f32(h));
            }
        }
    }

    f32x16 accO0 = (f32x16)0.0f;
    f32x16 accO1 = (f32x16)0.0f;
    float m_run = -1e30f;
    float l_run = 0.0f;

    const int srow = tid >> 3;
    const int scolu = (tid & 7) << 3;
    const int scsw = scolu ^ ((srow & 7) << 3);

    for (int kt = 0; kt < S_ / 32; ++kt) {
        const int tb = kt * 32;
        {
            const float* kp = Kb + (size_t)(tb + srow) * D_ + scolu;
            const float4 a = *(const float4*)(kp);
            const float4 b = *(const float4*)(kp + 4);
            float xs[8] = {a.x, a.y, a.z, a.w, b.x, b.y, b.z, b.w};
            short h8[8], l8[8];
#pragma unroll
            for (int j = 0; j < 8; ++j) {
                float x = phi(xs[j]);
                uint16_t h = f32_to_bf16_rn(x);
                h8[j] = (short)h;
                l8[j] = (short)f32_to_bf16_rn(x - bfbits_to_f32(h));
            }
            *(bf16x8*)&kh[srow][scsw] = *(const bf16x8*)h8;
            *(bf16x8*)&kl[srow][scsw] = *(const bf16x8*)l8;
        }
        __syncthreads();

        f32x16 accS = (f32x16)0.0f;
#pragma unroll
        for (int m = 0; m < 4; ++m) {
            const int c = (m * 16 + hi * 8) ^ ((ln31 & 7) << 3);
            bf16x8 kfh = *(const bf16x8*)&kh[ln31][c];
            bf16x8 kfl = *(const bf16x8*)&kl[ln31][c];
            accS = __builtin_amdgcn_mfma_f32_32x32x16_bf16(kfh, qfh[m], accS, 0, 0, 0);
            accS = __builtin_amdgcn_mfma_f32_32x32x16_bf16(kfh, qfl[m], accS, 0, 0, 0);
            accS = __builtin_amdgcn_mfma_f32_32x32x16_bf16(kfl, qfh[m], accS, 0, 0, 0);
        }

        float tmax = accS[0];
#pragma unroll
        for (int r = 1; r < 16; ++r) tmax = fmaxf(tmax, accS[r]);
        tmax = fmaxf(tmax, __shfl_xor(tmax, 32));
        const float m_new = fmaxf(m_run, tmax);
        const float corr = __expf(m_run - m_new);
        m_run = m_new;

        float p[16];
        float psum = 0.0f;
#pragma unroll
        for (int r = 0; r < 16; ++r) { p[r] = __expf(accS[r] - m_new); psum += p[r]; }
        l_run = l_run * corr + psum;

#pragma unroll
        for (int r = 0; r < 16; ++r) { accO0[r] *= corr; accO1[r] *= corr; }

        uint32_t pk[8];
#pragma unroll
        for (int k2 = 0; k2 < 8; ++k2)
            pk[k2] = (uint32_t)f32_to_bf16_rn(p[2 * k2]) |
                     ((uint32_t)f32_to_bf16_rn(p[2 * k2 + 1]) << 16);

        const uint32_t s0 = hi ? pk[0] : pk[2];
        const uint32_t s1 = hi ? pk[1] : pk[3];
        const uint32_t s2 = hi ? pk[4] : pk[6];
        const uint32_t s3 = hi ? pk[5] : pk[7];
        const uint32_t r0 = __shfl_xor(s0, 32);
        const uint32_t r1 = __shfl_xor(s1, 32);
        const uint32_t r2 = __shfl_xor(s2, 32);
        const uint32_t r3 = __shfl_xor(s3, 32);

        union U { uint32_t u[4]; bf16x8 v; };
        U f0, f1;
        f0.u[0] = hi ? r0 : pk[0];  f0.u[1] = hi ? r1 : pk[1];
        f0.u[2] = hi ? pk[2] : r0;  f0.u[3] = hi ? pk[3] : r1;
        f1.u[0] = hi ? r2 : pk[4];  f1.u[1] = hi ? r3 : pk[5];
        f1.u[2] = hi ? pk[6] : r2;  f1.u[3] = hi ? pk[7] : r3;

#pragma unroll
        for (int ts = 0; ts < 2; ++ts) {
            const bf16x8 pfv = ts ? f1.v : f0.v;
            const float* vp = Vb + (size_t)(tb + ts * 16 + hi * 8) * D_ + ln31;
#pragma unroll
            for (int dn = 0; dn < 2; ++dn) {
                bf16x8 vf;
#pragma unroll
                for (int j = 0; j < 8; ++j)
                    vf[j] = (short)f32_to_bf16_rn(vp[(size_t)j * D_ + dn * 32]);
                if (dn == 0) accO0 = __builtin_amdgcn_mfma_f32_32x32x16_bf16(vf, pfv, accO0, 0, 0, 0);
                else         accO1 = __builtin_amdgcn_mfma_f32_32x32x16_bf16(vf, pfv, accO1, 0, 0, 0);
            }
        }
        __syncthreads();
    }

    const float l_tot = l_run + __shfl_xor(l_run, 32);
    const float inv = 1.0f / l_tot;
    float* op = Ob + (size_t)(q0 + ln31) * D_;
#pragma unroll
    for (int g = 0; g < 4; ++g) {
        float4 o0, o1;
        o0.x = accO0[4 * g + 0] * inv; o0.y = accO0[4 * g + 1] * inv;
        o0.z = accO0[4 * g + 2] * inv; o0.w = accO0[4 * g + 3] * inv;
        o1.x = accO1[4 * g + 0] * inv; o1.y = accO1[4 * g + 1] * inv;
        o1.z = accO1[4 * g + 2] * inv; o1.w = accO1[4 * g + 3] * inv;
        *(float4*)(op + 8 * g + 4 * hi) = o0;
        *(float4*)(op + 32 + 8 * g + 4 * hi) = o1;
    }
}

extern "C" void kernel_launch(void* const* d_in, const int* in_sizes, int n_in,
                              void* d_out, int out_size, void* d_ws, size_t ws_size,
                              hipStream_t stream) {
    (void)in_sizes; (void)n_in; (void)out_size;
    const float* Q = (const float*)d_in[0];
    const float* K = (const float*)d_in[1];
    const float* V = (const float*)d_in[2];
    float* O = (float*)d_out;

    if (ws_size >= WS_NEED) {
        uint16_t* Kf = (uint16_t*)d_ws;
        uint16_t* Vt = (uint16_t*)((char*)d_ws + 1 * WS_ARR);
        prep_k<<<4096, 256, 0, stream>>>(K, Kf);
        prep_v<<<2048, 256, 0, stream>>>(V, Vt);
        la_attn8<<<512, 512, 0, stream>>>(Q, Kf, Vt, O);
    } else {
        la_attn_fwd<<<dim3(BH_, S_ / 128), 256, 0, stream>>>(Q, K, V, O);
    }
}

// Round 5
// 106.852 us; speedup vs baseline: 2.4514x; 2.4514x over previous
//
#include <hip/hip_runtime.h>
#include <stdint.h>

typedef __attribute__((ext_vector_type(8))) _Float16 f16x8;
typedef __attribute__((ext_vector_type(2))) _Float16 f16x2;
typedef __attribute__((ext_vector_type(8))) short bf16x8;
typedef __attribute__((ext_vector_type(16))) float f32x16;

#define BH_ 64
#define S_ 2048
#define D_ 64
#define KT_ 64
#define NT_ (S_ / KT_)
#define LOG2E 1.44269504088896340736f
// f16 P-fragment headroom: cvt_pkrtz overflows at 65504=2^16 -> THR=14 safe
// (p <= 2^14, PV accumulates in f32 C). Raising 8->14 makes the __all-gated
// wave-collective rescale RARE instead of near-every-tile.
#define DEFER_THR 14.0f

#define WS_ARR ((size_t)BH_ * S_ * D_ * 2)   // 16 MB per 16-bit array
#define WS_NEED (2 * WS_ARR)                 // Kf Vt

__device__ __forceinline__ uint16_t f32_to_bf16_rn(float f) {
    uint32_t u = __float_as_uint(f);
    u += 0x7fffu + ((u >> 16) & 1u);
    return (uint16_t)(u >> 16);
}
__device__ __forceinline__ float bfbits_to_f32(uint16_t h) {
    return __uint_as_float(((uint32_t)h) << 16);
}
__device__ __forceinline__ float phi(float x) { return x > 0.0f ? x + 1.0f : __expf(x); }

#if __has_builtin(__builtin_amdgcn_exp2f)
#define EXP2F(x) __builtin_amdgcn_exp2f(x)
#else
#define EXP2F(x) exp2f(x)
#endif

__device__ __forceinline__ float fmax3(float a, float b, float c) {
    float d;
    asm("v_max3_f32 %0, %1, %2, %3" : "=v"(d) : "v"(a), "v"(b), "v"(c));
    return d;
}

__device__ __forceinline__ uint32_t pkrtz(float lo, float hi2) {
    union {
        decltype(__builtin_amdgcn_cvt_pkrtz(0.0f, 0.0f)) v;
        uint32_t u;
    } c;
    c.v = __builtin_amdgcn_cvt_pkrtz(lo, hi2);
    return c.u;
}

// l-sum via packed dot: one v_dot2_f32_f16 per f16-pair replaces two v_add_f32,
// and makes the denominator use the SAME f16-rounded P as the numerator.
__device__ __forceinline__ float dot2acc(uint32_t p2, float acc) {
#if __has_builtin(__builtin_amdgcn_fdot2)
    union { uint32_t u; f16x2 v; } c;
    c.u = p2;
    const f16x2 one2 = {(_Float16)1.0f, (_Float16)1.0f};
    return __builtin_amdgcn_fdot2(c.v, one2, acc, false);
#else
    union { uint32_t u; f16x2 v; } c;
    c.u = p2;
    return acc + (float)c.v[0] + (float)c.v[1];
#endif
}

#define GLL16(gsrc, ldst)                                                              \
    __builtin_amdgcn_global_load_lds(                                                  \
        (const __attribute__((address_space(1))) uint32_t*)(gsrc),                     \
        (__attribute__((address_space(3))) uint32_t*)(ldst), 16, 0, 0)

// ---------------- pre-pass kernels ----------------
// Two-level slot swizzle: slot(t, c) = c ^ (t&7) ^ ((t>>3)&7).
// Level 1 (t&7) spreads the 8 rows of an octet; level 2 (t>>3) spreads the
// octets so lanes {l, l+8, l+16, l+24} (rows differing by 8) hit distinct
// 16B slots -> no 4-way ds_read_b128 bank conflicts.

__global__ void prep_k(const float* __restrict__ K, uint16_t* __restrict__ Kf) {
    const size_t e = ((size_t)blockIdx.x * 256 + threadIdx.x) * 8;
    const int d0 = (int)(e & 63);
    const int c = d0 >> 3;
    const int t = (int)((e >> 6) & 63);
    const size_t dst = e - d0 + (size_t)((c ^ (t & 7) ^ ((t >> 3) & 7)) * 8);
    const float4 a = *(const float4*)(K + e);
    const float4 b = *(const float4*)(K + e + 4);
    const float xs[8] = {a.x, a.y, a.z, a.w, b.x, b.y, b.z, b.w};
    _Float16 h8[8];
#pragma unroll
    for (int j = 0; j < 8; ++j) h8[j] = (_Float16)phi(xs[j]);
    *(f16x8*)(Kf + dst) = *(const f16x8*)h8;
}

// V^T with t-rows pre-permuted (tau: swap t-blocks [4..7] <-> [8..11] per 16)
// so P fragments feed PV's B-operand with NO cross-lane exchange.
__global__ void prep_v(const float* __restrict__ V, uint16_t* __restrict__ Vt) {
    const int bh = blockIdx.x >> 5, kt = blockIdx.x & 31;
    const int d = threadIdx.x >> 2;
    const size_t tile = (size_t)(bh * 32 + kt) * 4096;
    const float* vb = V + ((size_t)bh * S_ + (size_t)kt * KT_) * D_ + d;
#pragma unroll
    for (int cc = 0; cc < 2; ++cc) {
        const int ct = (threadIdx.x & 3) * 2 + cc;
        _Float16 v8[8];
#pragma unroll
        for (int i = 0; i < 8; ++i) {
            const int pos = 8 * ct + i;
            const int src = (pos & 48) | (4 * ((pos >> 3) & 1) + (pos & 3) + 8 * ((pos >> 2) & 1));
            v8[i] = (_Float16)vb[(size_t)src * D_];
        }
        *(f16x8*)(Vt + tile + (size_t)d * 64 +
                  (size_t)((ct ^ (d & 7) ^ ((d >> 3) & 7)) * 8)) = *(const f16x8*)v8;
    }
}

// ---------------- main kernel: 8 waves / 512 threads, 256 q-rows per block ----
// Round-0 structure (verified 108us). Register-neutral VALU cuts only:
//  (1) DEFER_THR 8 -> 14: wave-collective rescale (32 mul + 32 sub + exp)
//      goes from ~every tile to rare. Safe: p <= 2^14 < f16 max 2^16.
//  (2) v_max3_f32 tree: 31 -> ~20 ops, zero state.
//  (3) l-sum via v_dot2_f32_f16 on packed P fragments: 16 dot2 replace
//      32 v_add, denominator consistent with f16 numerator.

__global__ __launch_bounds__(512, 4)
void la_attn8(const float* __restrict__ Q, const uint16_t* __restrict__ Kf,
              const uint16_t* __restrict__ Vt, float* __restrict__ O)
{
    const int id = blockIdx.x;                 // 0..511
    const int wg = (id & 7) * 64 + (id >> 3);  // bijective XCD-chunked swizzle
    const int bh = wg >> 3;                    // 8 consecutive wg share one bh
    const int qt = wg & 7;
    const int tid = threadIdx.x;
    const int lane = tid & 63;
    const int wid = tid >> 6;                  // 0..7
    const int ln31 = lane & 31;
    const int hi = lane >> 5;
    const int sw = (ln31 & 7) ^ (ln31 >> 3);   // two-level read swizzle

    __shared__ __align__(16) uint16_t kf_s[2][4096];
    __shared__ __align__(16) uint16_t vt_s[2][4096];

    const int q0 = qt * 256 + wid * 32;

    // ---- Q: phi-map from raw fp32 in-kernel (once per block lifetime)
    f16x8 qf[4];
    {
        const float* qp = Q + ((size_t)bh * S_ + q0 + ln31) * 64;
#pragma unroll
        for (int m = 0; m < 4; ++m) {
            const float4 a = *(const float4*)(qp + m * 16 + hi * 8);
            const float4 b = *(const float4*)(qp + m * 16 + hi * 8 + 4);
            const float xs[8] = {a.x, a.y, a.z, a.w, b.x, b.y, b.z, b.w};
            _Float16 h8[8];
#pragma unroll
            for (int j = 0; j < 8; ++j) h8[j] = (_Float16)(phi(xs[j]) * LOG2E);
            qf[m] = *(const f16x8*)h8;
        }
    }

    // hoisted LDS element-offsets (rows ln31; +32-row read = same addr ^ 32)
    int off4[4];
#pragma unroll
    for (int m = 0; m < 4; ++m)
        off4[m] = ln31 * 64 + (((2 * m + hi) ^ sw) * 8);

    f32x16 accO0 = (f32x16)0.0f, accO1 = (f32x16)0.0f;
    float m_run = 0.0f, l_run = 0.0f;   // m_run=0: first tile takes rescale branch

    const size_t tb0 = (size_t)bh * 32 * 4096;

    auto stage = [&](int buf, int kt2) {
        const size_t toff = tb0 + (size_t)kt2 * 4096 + (size_t)tid * 8;
        GLL16(Kf + toff, &kf_s[buf][tid * 8]);
        GLL16(Vt + toff, &vt_s[buf][tid * 8]);
    };

    stage(0, 0);
    int cur = 0;

    for (int kt = 0; kt < NT_; ++kt) {
        __syncthreads();                     // buf[cur] loaded; buf[cur^1] free
        if (kt + 1 < NT_) stage(cur ^ 1, kt + 1);

        const uint16_t* __restrict__ kfp = kf_s[cur];
        const uint16_t* __restrict__ vtp = vt_s[cur];

        // ---- QK^T, swapped operands, single f16 pass; C-in biased with -m_run
        f32x16 s0, s1;
#pragma unroll
        for (int r = 0; r < 16; ++r) { s0[r] = -m_run; s1[r] = -m_run; }
        __builtin_amdgcn_s_setprio(1);
#pragma unroll
        for (int m = 0; m < 4; ++m) {
            f16x8 k0 = *(const f16x8*)&kfp[off4[m]];
            f16x8 k1 = *(const f16x8*)&kfp[(off4[m] ^ 32) + 2048];
            s0 = __builtin_amdgcn_mfma_f32_32x32x16_f16(k0, qf[m], s0, 0, 0, 0);
            s1 = __builtin_amdgcn_mfma_f32_32x32x16_f16(k1, qf[m], s1, 0, 0, 0);
        }
        __builtin_amdgcn_s_setprio(0);

        // ---- merged online softmax over all 64 k-rows (scores pre-shifted)
        float t8[8];
#pragma unroll
        for (int r = 0; r < 8; ++r)
            t8[r] = fmax3(fmaxf(s0[r], s0[r + 8]), s1[r], s1[r + 8]);
        const float ta = fmax3(t8[0], t8[1], t8[2]);
        const float tb = fmax3(t8[3], t8[4], t8[5]);
        const float tc = fmaxf(t8[6], t8[7]);
        float tmax = fmax3(ta, tb, tc);
        tmax = fmaxf(tmax, __shfl_xor(tmax, 32));   // = max(s) - m_run

        if (!__all(tmax <= DEFER_THR)) {     // T13 defer-max (now rare: THR=14)
            const float dlt = fmaxf(tmax, 0.0f);
            const float corr = EXP2F(-dlt);
            m_run += dlt;
            l_run *= corr;
#pragma unroll
            for (int r = 0; r < 16; ++r) {
                accO0[r] *= corr; accO1[r] *= corr;
                s0[r] -= dlt; s1[r] -= dlt;
            }
        }
#pragma unroll
        for (int r = 0; r < 16; ++r) {
            s0[r] = EXP2F(s0[r]);
            s1[r] = EXP2F(s1[r]);
        }

        // ---- P -> f16 fragments (no exchange: V is tau-permuted)
        union PF { uint32_t u[4]; f16x8 v; };
        PF pf[4];
#pragma unroll
        for (int i = 0; i < 4; ++i) {
            pf[0].u[i] = pkrtz(s0[2 * i], s0[2 * i + 1]);
            pf[1].u[i] = pkrtz(s0[8 + 2 * i], s0[9 + 2 * i]);
            pf[2].u[i] = pkrtz(s1[2 * i], s1[2 * i + 1]);
            pf[3].u[i] = pkrtz(s1[8 + 2 * i], s1[9 + 2 * i]);
        }

        // ---- l-sum on packed P (two chains to halve dep latency)
        float lsA = 0.0f, lsB = 0.0f;
#pragma unroll
        for (int i = 0; i < 4; ++i) {
            lsA = dot2acc(pf[0].u[i], lsA);
            lsB = dot2acc(pf[1].u[i], lsB);
            lsA = dot2acc(pf[2].u[i], lsA);
            lsB = dot2acc(pf[3].u[i], lsB);
        }
        l_run += lsA + lsB;

        // ---- PV: O^T += V'^T . P   (chunk c = sub*2 + ts)
        __builtin_amdgcn_s_setprio(1);
#pragma unroll
        for (int c = 0; c < 4; ++c) {
            f16x8 v0 = *(const f16x8*)&vtp[off4[c]];
            f16x8 v1 = *(const f16x8*)&vtp[(off4[c] ^ 32) + 2048];
            accO0 = __builtin_amdgcn_mfma_f32_32x32x16_f16(v0, pf[c].v, accO0, 0, 0, 0);
            accO1 = __builtin_amdgcn_mfma_f32_32x32x16_f16(v1, pf[c].v, accO1, 0, 0, 0);
        }
        __builtin_amdgcn_s_setprio(0);

        cur ^= 1;
    }

    // ---- epilogue: combine partner l, normalize, write O[q][d]
    const float l_tot = l_run + __shfl_xor(l_run, 32);
    const float inv = 1.0f / l_tot;
    float* op = O + ((size_t)bh * S_ + q0 + ln31) * D_;
#pragma unroll
    for (int g = 0; g < 4; ++g) {
        float4 o0, o1;
        o0.x = accO0[4 * g + 0] * inv; o0.y = accO0[4 * g + 1] * inv;
        o0.z = accO0[4 * g + 2] * inv; o0.w = accO0[4 * g + 3] * inv;
        o1.x = accO1[4 * g + 0] * inv; o1.y = accO1[4 * g + 1] * inv;
        o1.z = accO1[4 * g + 2] * inv; o1.w = accO1[4 * g + 3] * inv;
        *(float4*)(op + 8 * g + 4 * hi) = o0;
        *(float4*)(op + 32 + 8 * g + 4 * hi) = o1;
    }
}

// ---------------- fallback (round-1, self-contained) ----------------

__global__ __launch_bounds__(256, 2)
void la_attn_fwd(const float* __restrict__ Q, const float* __restrict__ K,
                 const float* __restrict__ V, float* __restrict__ O)
{
    const int bh = blockIdx.x;
    const int qt = blockIdx.y;
    const int tid = threadIdx.x;
    const int lane = tid & 63;
    const int wid = tid >> 6;
    const int ln31 = lane & 31;
    const int hi = lane >> 5;

    const size_t base = (size_t)bh * (S_ * D_);
    const float* __restrict__ Qb = Q + base;
    const float* __restrict__ Kb = K + base;
    const float* __restrict__ Vb = V + base;
    float* __restrict__ Ob = O + base;

    __shared__ __align__(16) uint16_t kh[32][D_];
    __shared__ __align__(16) uint16_t kl[32][D_];

    const int q0 = qt * 128 + wid * 32;

    bf16x8 qfh[4], qfl[4];
    {
        const float* qp = Qb + (size_t)(q0 + ln31) * D_;
#pragma unroll
        for (int m = 0; m < 4; ++m) {
            const float4 a = *(const float4*)(qp + m * 16 + hi * 8);
            const float4 b = *(const float4*)(qp + m * 16 + hi * 8 + 4);
            float xs[8] = {a.x, a.y, a.z, a.w, b.x, b.y, b.z, b.w};
#pragma unroll
            for (int j = 0; j < 8; ++j) {
                float x = phi(xs[j]);
                uint16_t h = f32_to_bf16_rn(x);
                qfh[m][j] = (short)h;
                qfl[m][j] = (short)f32_to_bf16_rn(x - bfbits_to_f32(h));
            }
        }
    }

    f32x16 accO0 = (f32x16)0.0f;
    f32x16 accO1 = (f32x16)0.0f;
    float m_run = -1e30f;
    float l_run = 0.0f;

    const int srow = tid >> 3;
    const int scolu = (tid & 7) << 3;
    const int scsw = scolu ^ ((srow & 7) << 3);

    for (int kt = 0; kt < S_ / 32; ++kt) {
        const int tb = kt * 32;
        {
            const float* kp = Kb + (size_t)(tb + srow) * D_ + scolu;
            const float4 a = *(const float4*)(kp);
            const float4 b = *(const float4*)(kp + 4);
            float xs[8] = {a.x, a.y, a.z, a.w, b.x, b.y, b.z, b.w};
            short h8[8], l8[8];
#pragma unroll
            for (int j = 0; j < 8; ++j) {
                float x = phi(xs[j]);
                uint16_t h = f32_to_bf16_rn(x);
                h8[j] = (short)h;
                l8[j] = (short)f32_to_bf16_rn(x - bfbits_to_f32(h));
            }
            *(bf16x8*)&kh[srow][scsw] = *(const bf16x8*)h8;
            *(bf16x8*)&kl[srow][scsw] = *(const bf16x8*)l8;
        }
        __syncthreads();

        f32x16 accS = (f32x16)0.0f;
#pragma unroll
        for (int m = 0; m < 4; ++m) {
            const int c = (m * 16 + hi * 8) ^ ((ln31 & 7) << 3);
            bf16x8 kfh = *(const bf16x8*)&kh[ln31][c];
            bf16x8 kfl = *(const bf16x8*)&kl[ln31][c];
            accS = __builtin_amdgcn_mfma_f32_32x32x16_bf16(kfh, qfh[m], accS, 0, 0, 0);
            accS = __builtin_amdgcn_mfma_f32_32x32x16_bf16(kfh, qfl[m], accS, 0, 0, 0);
            accS = __builtin_amdgcn_mfma_f32_32x32x16_bf16(kfl, qfh[m], accS, 0, 0, 0);
        }

        float tmax = accS[0];
#pragma unroll
        for (int r = 1; r < 16; ++r) tmax = fmaxf(tmax, accS[r]);
        tmax = fmaxf(tmax, __shfl_xor(tmax, 32));
        const float m_new = fmaxf(m_run, tmax);
        const float corr = __expf(m_run - m_new);
        m_run = m_new;

        float p[16];
        float psum = 0.0f;
#pragma unroll
        for (int r = 0; r < 16; ++r) { p[r] = __expf(accS[r] - m_new); psum += p[r]; }
        l_run = l_run * corr + psum;

#pragma unroll
        for (int r = 0; r < 16; ++r) { accO0[r] *= corr; accO1[r] *= corr; }

        uint32_t pk[8];
#pragma unroll
        for (int k2 = 0; k2 < 8; ++k2)
            pk[k2] = (uint32_t)f32_to_bf16_rn(p[2 * k2]) |
                     ((uint32_t)f32_to_bf16_rn(p[2 * k2 + 1]) << 16);

        const uint32_t s0 = hi ? pk[0] : pk[2];
        const uint32_t s1 = hi ? pk[1] : pk[3];
        const uint32_t s2 = hi ? pk[4] : pk[6];
        const uint32_t s3 = hi ? pk[5] : pk[7];
        const uint32_t r0 = __shfl_xor(s0, 32);
        const uint32_t r1 = __shfl_xor(s1, 32);
        const uint32_t r2 = __shfl_xor(s2, 32);
        const uint32_t r3 = __shfl_xor(s3, 32);

        union U { uint32_t u[4]; bf16x8 v; };
        U f0, f1;
        f0.u[0] = hi ? r0 : pk[0];  f0.u[1] = hi ? r1 : pk[1];
        f0.u[2] = hi ? pk[2] : r0;  f0.u[3] = hi ? pk[3] : r1;
        f1.u[0] = hi ? r2 : pk[4];  f1.u[1] = hi ? r3 : pk[5];
        f1.u[2] = hi ? pk[6] : r2;  f1.u[3] = hi ? pk[7] : r3;

#pragma unroll
        for (int ts = 0; ts < 2; ++ts) {
            const bf16x8 pfv = ts ? f1.v : f0.v;
            const float* vp = Vb + (size_t)(tb + ts * 16 + hi * 8) * D_ + ln31;
#pragma unroll
            for (int dn = 0; dn < 2; ++dn) {
                bf16x8 vf;
#pragma unroll
                for (int j = 0; j < 8; ++j)
                    vf[j] = (short)f32_to_bf16_rn(vp[(size_t)j * D_ + dn * 32]);
                if (dn == 0) accO0 = __builtin_amdgcn_mfma_f32_32x32x16_bf16(vf, pfv, accO0, 0, 0, 0);
                else         accO1 = __builtin_amdgcn_mfma_f32_32x32x16_bf16(vf, pfv, accO1, 0, 0, 0);
            }
        }
        __syncthreads();
    }

    const float l_tot = l_run + __shfl_xor(l_run, 32);
    const float inv = 1.0f / l_tot;
    float* op = Ob + (size_t)(q0 + ln31) * D_;
#pragma unroll
    for (int g = 0; g < 4; ++g) {
        float4 o0, o1;
        o0.x = accO0[4 * g + 0] * inv; o0.y = accO0[4 * g + 1] * inv;
        o0.z = accO0[4 * g + 2] * inv; o0.w = accO0[4 * g + 3] * inv;
        o1.x = accO1[4 * g + 0] * inv; o1.y = accO1[4 * g + 1] * inv;
        o1.z = accO1[4 * g + 2] * inv; o1.w = accO1[4 * g + 3] * inv;
        *(float4*)(op + 8 * g + 4 * hi) = o0;
        *(float4*)(op + 32 + 8 * g + 4 * hi) = o1;
    }
}

extern "C" void kernel_launch(void* const* d_in, const int* in_sizes, int n_in,
                              void* d_out, int out_size, void* d_ws, size_t ws_size,
                              hipStream_t stream) {
    (void)in_sizes; (void)n_in; (void)out_size;
    const float* Q = (const float*)d_in[0];
    const float* K = (const float*)d_in[1];
    const float* V = (const float*)d_in[2];
    float* O = (float*)d_out;

    if (ws_size >= WS_NEED) {
        uint16_t* Kf = (uint16_t*)d_ws;
        uint16_t* Vt = (uint16_t*)((char*)d_ws + 1 * WS_ARR);
        prep_k<<<4096, 256, 0, stream>>>(K, Kf);
        prep_v<<<2048, 256, 0, stream>>>(V, Vt);
        la_attn8<<<512, 512, 0, stream>>>(Q, Kf, Vt, O);
    } else {
        la_attn_fwd<<<dim3(BH_, S_ / 128), 256, 0, stream>>>(Q, K, V, O);
    }
}